// Round 2
// baseline (506.910 us; speedup 1.0000x reference)
//
#include <hip/hip_runtime.h>

typedef unsigned short u16;
typedef __bf16 bf16x8 __attribute__((ext_vector_type(8)));
typedef float f32x4 __attribute__((ext_vector_type(4)));

__device__ __forceinline__ u16 f2bf(float f) {
  union { float f; unsigned int u; } v; v.f = f;
  unsigned int u = v.u;
  u += 0x7fffu + ((u >> 16) & 1u);
  return (u16)(u >> 16);
}
__device__ __forceinline__ float bf2f(u16 h) {
  union { unsigned int u; float f; } v; v.u = ((unsigned int)h) << 16; return v.f;
}

// ---------------- cast weights fp32 -> bf16 ----------------
__global__ __launch_bounds__(256) void cast_weights(
    const float* __restrict__ w0, const float* __restrict__ w1,
    const float* __restrict__ w2, const float* __restrict__ w3,
    u16* __restrict__ o0, u16* __restrict__ o1,
    u16* __restrict__ o2, u16* __restrict__ o3) {
  int i = blockIdx.x * 256 + threadIdx.x;
  if (i < 110592) o0[i] = f2bf(w0[i]);   // qkv_w 576x192
  if (i < 36864)  o1[i] = f2bf(w1[i]);   // proj_w 192x192
  if (i < 221184) o2[i] = f2bf(w2[i]);   // fc1_w 1152x192
  if (i < 221184) o3[i] = f2bf(w3[i]);   // fc2_w 192x1152
}

// ---------------- bias table [6][64(key m)][64(query r)]; key>=49 -> -1e30 ----
__global__ __launch_bounds__(256) void build_btab(
    const float* __restrict__ rpb, float* __restrict__ btab) {
  int id = blockIdx.x * 256 + threadIdx.x;   // 96*256 = 24576
  int head = id >> 12;
  int m = (id >> 6) & 63;
  int r = id & 63;
  float v;
  if (m >= 49) v = -1e30f;                   // key mask folds into bias
  else if (r >= 49) v = 0.0f;
  else {
    int mi = m / 7, mj = m - mi * 7;
    int ri = r / 7, rj = r - ri * 7;
    v = rpb[((ri - mi + 6) * 13 + (rj - mj + 6)) * 6 + head];
  }
  btab[id] = v;
}

// ---------------- layernorm (fp32 in, bf16 out), 1 wave per row of 192 ----------------
__global__ __launch_bounds__(256) void ln_kernel(
    const float* __restrict__ x, const float* __restrict__ g,
    const float* __restrict__ b, u16* __restrict__ out) {
  int row = blockIdx.x * 4 + (threadIdx.x >> 6);
  int lane = threadIdx.x & 63;
  const float* xr = x + (long)row * 192;
  float e0 = xr[lane], e1 = xr[lane + 64], e2 = xr[lane + 128];
  float s = e0 + e1 + e2;
  #pragma unroll
  for (int o = 1; o < 64; o <<= 1) s += __shfl_xor(s, o);
  float mean = s * (1.0f / 192.0f);
  float d0 = e0 - mean, d1 = e1 - mean, d2 = e2 - mean;
  float q = d0 * d0 + d1 * d1 + d2 * d2;
  #pragma unroll
  for (int o = 1; o < 64; o <<= 1) q += __shfl_xor(q, o);
  float rstd = rsqrtf(q * (1.0f / 192.0f) + 1e-5f);
  u16* orow = out + (long)row * 192;
  orow[lane]       = f2bf(d0 * rstd * g[lane]       + b[lane]);
  orow[lane + 64]  = f2bf(d1 * rstd * g[lane + 64]  + b[lane + 64]);
  orow[lane + 128] = f2bf(d2 * rstd * g[lane + 128] + b[lane + 128]);
}

// ---------------- MFMA GEMM: out[M,N] = A[M,K] @ W[N,K]^T + bias ----------------
// Block = 2x2 waves; wave tile = (MT*16) x (NT*16) in 16x16x32 bf16 MFMAs.
// MODE 0: store bf16. MODE 1: GELU(exact) -> bf16. MODE 2: +resid(fp32) -> fp32.
template<int MODE, int MT, int NT>
__global__ __launch_bounds__(256) void gemm_kernel(
    const u16* __restrict__ A, const u16* __restrict__ W,
    const float* __restrict__ bias, const float* __restrict__ resid,
    void* __restrict__ out, int N, int K) {
  __shared__ u16 lA[MT * 32 * 40];   // stride 40 u16 (80B): conflict-free frag reads
  __shared__ u16 lB[NT * 32 * 40];
  int tid = threadIdx.x;
  int wave = tid >> 6, lane = tid & 63;
  int wm = wave >> 1, wn = wave & 1;
  int quad = lane >> 4, l15 = lane & 15;
  long bm = (long)blockIdx.x * (MT * 32);
  int bn = blockIdx.y * (NT * 32);
  int r = tid >> 2, cg = (tid & 3) * 8;
  f32x4 acc[MT][NT] = {};
  for (int k0 = 0; k0 < K; k0 += 32) {
    uint4 av[MT / 2], bv[NT / 2];
    #pragma unroll
    for (int i = 0; i < MT / 2; i++)
      av[i] = *(const uint4*)(A + (bm + i * 64 + r) * K + k0 + cg);
    #pragma unroll
    for (int i = 0; i < NT / 2; i++)
      bv[i] = *(const uint4*)(W + (long)(bn + i * 64 + r) * K + k0 + cg);
    __syncthreads();
    #pragma unroll
    for (int i = 0; i < MT / 2; i++) *(uint4*)&lA[(i * 64 + r) * 40 + cg] = av[i];
    #pragma unroll
    for (int i = 0; i < NT / 2; i++) *(uint4*)&lB[(i * 64 + r) * 40 + cg] = bv[i];
    __syncthreads();
    bf16x8 af[MT], bfr[NT];
    #pragma unroll
    for (int mt = 0; mt < MT; mt++)
      af[mt] = *(const bf16x8*)&lA[(wm * (MT * 16) + mt * 16 + l15) * 40 + quad * 8];
    #pragma unroll
    for (int nt = 0; nt < NT; nt++)
      bfr[nt] = *(const bf16x8*)&lB[(wn * (NT * 16) + nt * 16 + l15) * 40 + quad * 8];
    #pragma unroll
    for (int mt = 0; mt < MT; mt++)
      #pragma unroll
      for (int nt = 0; nt < NT; nt++)
        acc[mt][nt] = __builtin_amdgcn_mfma_f32_16x16x32_bf16(af[mt], bfr[nt], acc[mt][nt], 0, 0, 0);
  }
  #pragma unroll
  for (int mt = 0; mt < MT; mt++) {
    #pragma unroll
    for (int nt = 0; nt < NT; nt++) {
      int col = bn + wn * (NT * 16) + nt * 16 + l15;
      float bi = bias[col];
      #pragma unroll
      for (int j = 0; j < 4; j++) {
        long row = bm + wm * (MT * 16) + mt * 16 + quad * 4 + j;
        float v = acc[mt][nt][j] + bi;
        long idx = row * N + col;
        if (MODE == 0) {
          ((u16*)out)[idx] = f2bf(v);
        } else if (MODE == 1) {
          v = 0.5f * v * (1.0f + erff(v * 0.70710678118f));
          ((u16*)out)[idx] = f2bf(v);
        } else {
          ((float*)out)[idx] = resid[idx] + v;
        }
      }
    }
  }
}

// ---------------- MFMA windowed attention: 1 wave per (window, head) ----------------
// S^T = K @ Q^T (so softmax reduces across quads only), P round-trips LDS packed,
// O = P @ V via Vt (transposed-at-load V). Shift handled via token index math.
__global__ __launch_bounds__(256) void attn_kernel(
    const u16* __restrict__ qkv, const float* __restrict__ btab,
    u16* __restrict__ attn) {
  // per-wave region (u16 units):
  //  [0,2560)    Q  64 rows x stride 40   } overlaid by P (64 x stride 72 = 4608)
  //  [2560,5120) K  64 rows x stride 40   }
  //  [5120,7424) Vt 32 rows x stride 72
  //  [7424,7552) rsum recip (64 fp32)
  __shared__ u16 lds[4 * 7552];   // 60416 B
  int tid = threadIdx.x;
  int wave = tid >> 6, lane = tid & 63;
  int quad = lane >> 4, l15 = lane & 15;
  int w = blockIdx.x * 4 + wave;
  int win = w / 6, head = w - win * 6;
  int b = win >> 6, wy = (win >> 3) & 7, wx = win & 7;
  u16* lq = lds + wave * 7552;
  u16* lk = lq + 2560;
  u16* lvt = lq + 5120;
  float* rsum = (float*)(lq + 7424);
  u16* lp = lq;

  // ---- stage Q,K,V (rows >=49 zero-filled; V transposed) ----
  #pragma unroll
  for (int p = 0; p < 4; p++) {
    int n = p * 16 + (lane >> 2);
    int qtr = (lane & 3) * 8;
    uint4 qv = {}, kv = {}, vv = {};
    if (n < 49) {
      int i = n / 7, j = n - i * 7;
      int y = wy * 7 + i + 3;  if (y >= 56) y -= 56;
      int xx = wx * 7 + j + 3; if (xx >= 56) xx -= 56;
      long base = ((long)(b * 3136 + y * 56 + xx)) * 576 + head * 32 + qtr;
      qv = *(const uint4*)(qkv + base);
      kv = *(const uint4*)(qkv + base + 192);
      vv = *(const uint4*)(qkv + base + 384);
    }
    *(uint4*)&lq[n * 40 + qtr] = qv;
    *(uint4*)&lk[n * 40 + qtr] = kv;
    const u16* vp = (const u16*)&vv;
    #pragma unroll
    for (int d = 0; d < 8; d++) lvt[(qtr + d) * 72 + n] = vp[d];
  }
  __syncthreads();

  // ---- S^T[key m][query r] = K @ Q^T ----
  bf16x8 ka[4], qb[4];
  #pragma unroll
  for (int t = 0; t < 4; t++) {
    ka[t] = *(const bf16x8*)&lk[(t * 16 + l15) * 40 + quad * 8];
    qb[t] = *(const bf16x8*)&lq[(t * 16 + l15) * 40 + quad * 8];
  }
  f32x4 s[4][4];
  const f32x4 fz = {0.0f, 0.0f, 0.0f, 0.0f};
  #pragma unroll
  for (int tm = 0; tm < 4; tm++)
    #pragma unroll
    for (int tr = 0; tr < 4; tr++)
      s[tm][tr] = __builtin_amdgcn_mfma_f32_16x16x32_bf16(ka[tm], qb[tr], fz, 0, 0, 0);

  // ---- scale + bias(+mask) ----
  const float scale = 0.17677669529663687f;  // 32^-0.5
  const float* bt = btab + head * 4096;
  float mx[4] = {-1e30f, -1e30f, -1e30f, -1e30f};
  #pragma unroll
  for (int tm = 0; tm < 4; tm++) {
    int m0 = tm * 16 + quad * 4;
    #pragma unroll
    for (int tr = 0; tr < 4; tr++) {
      int r = tr * 16 + l15;
      #pragma unroll
      for (int j = 0; j < 4; j++) {
        float v = s[tm][tr][j] * scale + bt[(m0 + j) * 64 + r];
        s[tm][tr][j] = v;
        mx[tr] = fmaxf(mx[tr], v);
      }
    }
  }
  #pragma unroll
  for (int tr = 0; tr < 4; tr++) {
    mx[tr] = fmaxf(mx[tr], __shfl_xor(mx[tr], 16));
    mx[tr] = fmaxf(mx[tr], __shfl_xor(mx[tr], 32));
  }
  // ---- exp, pack P (bf16, unnormalized) to LDS; accumulate row sums ----
  float sm[4] = {0.f, 0.f, 0.f, 0.f};
  #pragma unroll
  for (int tm = 0; tm < 4; tm++) {
    #pragma unroll
    for (int tr = 0; tr < 4; tr++) {
      int r = tr * 16 + l15;
      float e0 = __expf(s[tm][tr][0] - mx[tr]);
      float e1 = __expf(s[tm][tr][1] - mx[tr]);
      float e2 = __expf(s[tm][tr][2] - mx[tr]);
      float e3 = __expf(s[tm][tr][3] - mx[tr]);
      sm[tr] += (e0 + e1) + (e2 + e3);
      uint2 pk;
      pk.x = (unsigned int)f2bf(e0) | ((unsigned int)f2bf(e1) << 16);
      pk.y = (unsigned int)f2bf(e2) | ((unsigned int)f2bf(e3) << 16);
      *(uint2*)&lp[r * 72 + tm * 16 + quad * 4] = pk;
    }
  }
  #pragma unroll
  for (int tr = 0; tr < 4; tr++) {
    sm[tr] += __shfl_xor(sm[tr], 16);
    sm[tr] += __shfl_xor(sm[tr], 32);
  }
  if (quad == 0) {
    #pragma unroll
    for (int tr = 0; tr < 4; tr++) rsum[tr * 16 + l15] = 1.0f / sm[tr];
  }
  __syncthreads();

  // ---- O[r][d] = P @ V via Vt ----
  f32x4 o[4][2] = {};
  #pragma unroll
  for (int ks = 0; ks < 2; ks++) {
    bf16x8 vb0 = *(const bf16x8*)&lvt[(l15) * 72 + ks * 32 + quad * 8];
    bf16x8 vb1 = *(const bf16x8*)&lvt[(16 + l15) * 72 + ks * 32 + quad * 8];
    #pragma unroll
    for (int rt = 0; rt < 4; rt++) {
      bf16x8 pf = *(const bf16x8*)&lp[(rt * 16 + l15) * 72 + ks * 32 + quad * 8];
      o[rt][0] = __builtin_amdgcn_mfma_f32_16x16x32_bf16(pf, vb0, o[rt][0], 0, 0, 0);
      o[rt][1] = __builtin_amdgcn_mfma_f32_16x16x32_bf16(pf, vb1, o[rt][1], 0, 0, 0);
    }
  }
  // ---- normalize + scatter back through inverse shift ----
  #pragma unroll
  for (int rt = 0; rt < 4; rt++) {
    #pragma unroll
    for (int j = 0; j < 4; j++) {
      int r = rt * 16 + quad * 4 + j;
      if (r < 49) {
        float inv = rsum[r];
        int i = r / 7, jj = r - i * 7;
        int y = wy * 7 + i + 3;   if (y >= 56) y -= 56;
        int xx = wx * 7 + jj + 3; if (xx >= 56) xx -= 56;
        long base = ((long)(b * 3136 + y * 56 + xx)) * 192 + head * 32 + l15;
        attn[base]      = f2bf(o[rt][0][j] * inv);
        attn[base + 16] = f2bf(o[rt][1][j] * inv);
      }
    }
  }
}

extern "C" void kernel_launch(void* const* d_in, const int* in_sizes, int n_in,
                              void* d_out, int out_size, void* d_ws, size_t ws_size,
                              hipStream_t stream) {
  (void)in_sizes; (void)n_in; (void)out_size; (void)ws_size;
  const float* x      = (const float*)d_in[0];
  const float* ln1_g  = (const float*)d_in[3];
  const float* ln1_b  = (const float*)d_in[4];
  const float* qkv_w  = (const float*)d_in[5];
  const float* qkv_b  = (const float*)d_in[6];
  const float* rpb    = (const float*)d_in[7];
  const float* proj_w = (const float*)d_in[8];
  const float* proj_b = (const float*)d_in[9];
  const float* ln2_g  = (const float*)d_in[10];
  const float* ln2_b  = (const float*)d_in[11];
  const float* fc1_w  = (const float*)d_in[12];
  const float* fc1_b  = (const float*)d_in[13];
  const float* fc2_w  = (const float*)d_in[14];
  const float* fc2_b  = (const float*)d_in[15];

  // workspace layout (bytes), M=50176:
  //   [0,            38,535,168)  x2 fp32
  //   [38,535,168,   57,802,752)  hA bf16 (ln1 out; btab overlays after qkv GEMM;
  //                               region rewritten as ln2 out later)
  //   [57,802,752,  115,605,504)  qkv bf16  --+ dead after proj; hid bf16 overlays
  //   [115,605,504, 134,873,088)  attn bf16 --+ [57,802,752, 173,408,256)
  //   [173,408,256, 174,587,904)  bf16 weights
  char* ws = (char*)d_ws;
  float* x2   = (float*)(ws + 0);
  u16* hA     = (u16*)(ws + 38535168);
  float* btab = (float*)(ws + 38535168);   // 98,304 B, live only qkv->attn
  u16* qkv    = (u16*)(ws + 57802752);
  u16* attn   = (u16*)(ws + 115605504);
  u16* hid    = (u16*)(ws + 57802752);
  u16* wbuf   = (u16*)(ws + 173408256);
  u16* qkv_wb  = wbuf;
  u16* proj_wb = wbuf + 110592;
  u16* fc1_wb  = wbuf + 147456;
  u16* fc2_wb  = wbuf + 368640;

  cast_weights<<<dim3(864), 256, 0, stream>>>(qkv_w, proj_w, fc1_w, fc2_w,
                                              qkv_wb, proj_wb, fc1_wb, fc2_wb);
  ln_kernel<<<dim3(12544), 256, 0, stream>>>(x, ln1_g, ln1_b, hA);
  gemm_kernel<0, 4, 2><<<dim3(392, 9), 256, 0, stream>>>(hA, qkv_wb, qkv_b, nullptr,
                                                         qkv, 576, 192);
  build_btab<<<dim3(96), 256, 0, stream>>>(rpb, btab);
  attn_kernel<<<dim3(1536), 256, 0, stream>>>(qkv, btab, attn);
  gemm_kernel<2, 4, 2><<<dim3(392, 3), 256, 0, stream>>>(attn, proj_wb, proj_b, x,
                                                         x2, 192, 192);
  ln_kernel<<<dim3(12544), 256, 0, stream>>>(x2, ln2_g, ln2_b, hA);
  gemm_kernel<1, 4, 4><<<dim3(392, 9), 256, 0, stream>>>(hA, fc1_wb, fc1_b, nullptr,
                                                         hid, 1152, 192);
  gemm_kernel<2, 4, 2><<<dim3(392, 3), 256, 0, stream>>>(hid, fc2_wb, fc2_b, x2,
                                                         (float*)d_out, 192, 1152);
}

// Round 3
// 427.087 us; speedup vs baseline: 1.1869x; 1.1869x over previous
//
#include <hip/hip_runtime.h>

typedef unsigned short u16;
typedef __bf16 bf16x8 __attribute__((ext_vector_type(8)));
typedef float f32x4 __attribute__((ext_vector_type(4)));

#define AS1 __attribute__((address_space(1)))
#define AS3 __attribute__((address_space(3)))

__device__ __forceinline__ void gld16(const void* g, void* l) {
  // 16B per lane: global per-lane gather -> LDS (wave-uniform base + lane*16)
  __builtin_amdgcn_global_load_lds((const AS1 void*)g, (AS3 void*)l, 16, 0, 0);
}

__device__ __forceinline__ u16 f2bf(float f) {
  union { float f; unsigned int u; } v; v.f = f;
  unsigned int u = v.u;
  u += 0x7fffu + ((u >> 16) & 1u);
  return (u16)(u >> 16);
}
__device__ __forceinline__ float bf2f(u16 h) {
  union { unsigned int u; float f; } v; v.u = ((unsigned int)h) << 16; return v.f;
}

// ---------------- cast weights fp32 -> bf16 ----------------
__global__ __launch_bounds__(256) void cast_weights(
    const float* __restrict__ w0, const float* __restrict__ w1,
    const float* __restrict__ w2, const float* __restrict__ w3,
    u16* __restrict__ o0, u16* __restrict__ o1,
    u16* __restrict__ o2, u16* __restrict__ o3) {
  int i = blockIdx.x * 256 + threadIdx.x;
  if (i < 110592) o0[i] = f2bf(w0[i]);   // qkv_w 576x192
  if (i < 36864)  o1[i] = f2bf(w1[i]);   // proj_w 192x192
  if (i < 221184) o2[i] = f2bf(w2[i]);   // fc1_w 1152x192
  if (i < 221184) o3[i] = f2bf(w3[i]);   // fc2_w 192x1152
}

// ---------------- bias table [6][64(key m)][64(query r)]; key>=49 -> -1e30 ----
__global__ __launch_bounds__(256) void build_btab(
    const float* __restrict__ rpb, float* __restrict__ btab) {
  int id = blockIdx.x * 256 + threadIdx.x;   // 96*256 = 24576
  int head = id >> 12;
  int m = (id >> 6) & 63;
  int r = id & 63;
  float v;
  if (m >= 49) v = -1e30f;                   // key mask folds into bias
  else if (r >= 49) v = 0.0f;
  else {
    int mi = m / 7, mj = m - mi * 7;
    int ri = r / 7, rj = r - ri * 7;
    v = rpb[((ri - mi + 6) * 13 + (rj - mj + 6)) * 6 + head];
  }
  btab[id] = v;
}

// ---------------- layernorm (fp32 in, bf16 out), 1 wave per row of 192 ----------------
__global__ __launch_bounds__(256) void ln_kernel(
    const float* __restrict__ x, const float* __restrict__ g,
    const float* __restrict__ b, u16* __restrict__ out) {
  int row = blockIdx.x * 4 + (threadIdx.x >> 6);
  int lane = threadIdx.x & 63;
  const float* xr = x + (long)row * 192;
  float e0 = xr[lane], e1 = xr[lane + 64], e2 = xr[lane + 128];
  float s = e0 + e1 + e2;
  #pragma unroll
  for (int o = 1; o < 64; o <<= 1) s += __shfl_xor(s, o);
  float mean = s * (1.0f / 192.0f);
  float d0 = e0 - mean, d1 = e1 - mean, d2 = e2 - mean;
  float q = d0 * d0 + d1 * d1 + d2 * d2;
  #pragma unroll
  for (int o = 1; o < 64; o <<= 1) q += __shfl_xor(q, o);
  float rstd = rsqrtf(q * (1.0f / 192.0f) + 1e-5f);
  u16* orow = out + (long)row * 192;
  orow[lane]       = f2bf(d0 * rstd * g[lane]       + b[lane]);
  orow[lane + 64]  = f2bf(d1 * rstd * g[lane + 64]  + b[lane + 64]);
  orow[lane + 128] = f2bf(d2 * rstd * g[lane + 128] + b[lane + 128]);
}

// ---------------- MFMA GEMM: out[M,N] = A[M,K] @ W[N,K]^T + bias ----------------
// Block tile 128x64, 4 waves 2x2 (wave tile 64x32), 16x16x32 bf16 MFMA.
// Full-K=192 chunk staged fragment-ordered via global_load_lds (conflict-free
// ds_read_b128 at lane*16). K must be a multiple of 192 (loop chunks for fc2).
// Epilogue: acc -> LDS fp32 tile (stride 66: conflict-optimal both directions)
// -> full-line coalesced global stores.
// MODE 0: store bf16. MODE 1: GELU(exact) -> bf16. MODE 2: +resid(fp32) -> fp32.
template<int MODE>
__global__ __launch_bounds__(256) void gemm_kernel(
    const u16* __restrict__ A, const u16* __restrict__ W,
    const float* __restrict__ bias, const float* __restrict__ resid,
    void* __restrict__ out, int N, int K) {
  // A: 48 tiles (mt' 0..7, kt 0..5) of 512 u16; B: 24 tiles (nt' 0..3, kt 0..5)
  __shared__ u16 lds[36864];           // 73,728 B
  float* ct = (float*)lds;             // epilogue overlay: 128 x 66 fp32 (33,792 B)
  int tid = threadIdx.x;
  int wave = tid >> 6, lane = tid & 63;
  int wm = wave >> 1, wn = wave & 1;
  int quad = lane >> 4, l15 = lane & 15;
  long bm = (long)blockIdx.x * 128;
  int bn = blockIdx.y * 64;

  f32x4 acc[4][2] = {};
  for (int kc = 0; kc < K; kc += 192) {
    if (kc > 0) __syncthreads();       // protect LDS reuse across chunks
    // ---- stage: 72 tiles, 18 per wave, fragment-ordered ----
    int t0 = wave * 18;
    #pragma unroll
    for (int ti = 0; ti < 18; ti++) {
      int t = t0 + ti;
      int isB = t >= 48;
      int tt = isB ? t - 48 : t;
      int grp = tt / 6, kt = tt - grp * 6;
      const u16* g = isB
          ? (W + (long)(bn + grp * 16 + l15) * K + kc + kt * 32 + quad * 8)
          : (A + (bm + grp * 16 + l15) * K + kc + kt * 32 + quad * 8);
      gld16(g, &lds[(isB ? 24576 : 0) + tt * 512]);
    }
    __syncthreads();
    // ---- compute: 6 kt steps x 8 MFMA ----
    #pragma unroll
    for (int kt = 0; kt < 6; kt++) {
      bf16x8 af[4], bfr[2];
      #pragma unroll
      for (int mt = 0; mt < 4; mt++)
        af[mt] = *(const bf16x8*)&lds[((wm * 4 + mt) * 6 + kt) * 512 + lane * 8];
      #pragma unroll
      for (int nt = 0; nt < 2; nt++)
        bfr[nt] = *(const bf16x8*)&lds[24576 + ((wn * 2 + nt) * 6 + kt) * 512 + lane * 8];
      #pragma unroll
      for (int mt = 0; mt < 4; mt++)
        #pragma unroll
        for (int nt = 0; nt < 2; nt++)
          acc[mt][nt] = __builtin_amdgcn_mfma_f32_16x16x32_bf16(af[mt], bfr[nt], acc[mt][nt], 0, 0, 0);
    }
  }
  __syncthreads();
  // ---- epilogue: acc(+bias) -> LDS fp32 [128][66] ----
  #pragma unroll
  for (int nt = 0; nt < 2; nt++) {
    int col = wn * 32 + nt * 16 + l15;
    float bi = bias[bn + col];
    #pragma unroll
    for (int mt = 0; mt < 4; mt++) {
      int row0 = wm * 64 + mt * 16 + quad * 4;
      #pragma unroll
      for (int j = 0; j < 4; j++)
        ct[(row0 + j) * 66 + col] = acc[mt][nt][j] + bi;
    }
  }
  __syncthreads();
  // ---- coalesced writeout: 2048 float4 chunks (128 rows x 16 groups) ----
  #pragma unroll
  for (int it = 0; it < 8; it++) {
    int c = it * 256 + tid;
    int row = c >> 4, cg = (c & 15) * 4;
    float4 v = *(const float4*)&ct[row * 66 + cg];
    long idx = (bm + row) * (long)N + bn + cg;
    if (MODE == 2) {
      const float4 rv = *(const float4*)(resid + idx);
      v.x += rv.x; v.y += rv.y; v.z += rv.z; v.w += rv.w;
      *(float4*)((float*)out + idx) = v;
    } else {
      if (MODE == 1) {
        v.x = 0.5f * v.x * (1.0f + erff(v.x * 0.70710678118f));
        v.y = 0.5f * v.y * (1.0f + erff(v.y * 0.70710678118f));
        v.z = 0.5f * v.z * (1.0f + erff(v.z * 0.70710678118f));
        v.w = 0.5f * v.w * (1.0f + erff(v.w * 0.70710678118f));
      }
      uint2 pk;
      pk.x = (unsigned int)f2bf(v.x) | ((unsigned int)f2bf(v.y) << 16);
      pk.y = (unsigned int)f2bf(v.z) | ((unsigned int)f2bf(v.w) << 16);
      *(uint2*)((u16*)out + idx) = pk;
    }
  }
}

// ---------------- MFMA windowed attention: 1 wave per (window, head) ----------------
__global__ __launch_bounds__(256) void attn_kernel(
    const u16* __restrict__ qkv, const float* __restrict__ btab,
    u16* __restrict__ attn) {
  __shared__ u16 lds[4 * 7552];   // 60416 B
  int tid = threadIdx.x;
  int wave = tid >> 6, lane = tid & 63;
  int quad = lane >> 4, l15 = lane & 15;
  int w = blockIdx.x * 4 + wave;
  int win = w / 6, head = w - win * 6;
  int b = win >> 6, wy = (win >> 3) & 7, wx = win & 7;
  u16* lq = lds + wave * 7552;
  u16* lk = lq + 2560;
  u16* lvt = lq + 5120;
  float* rsum = (float*)(lq + 7424);
  u16* lp = lq;

  #pragma unroll
  for (int p = 0; p < 4; p++) {
    int n = p * 16 + (lane >> 2);
    int qtr = (lane & 3) * 8;
    uint4 qv = {}, kv = {}, vv = {};
    if (n < 49) {
      int i = n / 7, j = n - i * 7;
      int y = wy * 7 + i + 3;  if (y >= 56) y -= 56;
      int xx = wx * 7 + j + 3; if (xx >= 56) xx -= 56;
      long base = ((long)(b * 3136 + y * 56 + xx)) * 576 + head * 32 + qtr;
      qv = *(const uint4*)(qkv + base);
      kv = *(const uint4*)(qkv + base + 192);
      vv = *(const uint4*)(qkv + base + 384);
    }
    *(uint4*)&lq[n * 40 + qtr] = qv;
    *(uint4*)&lk[n * 40 + qtr] = kv;
    const u16* vp = (const u16*)&vv;
    #pragma unroll
    for (int d = 0; d < 8; d++) lvt[(qtr + d) * 72 + n] = vp[d];
  }
  __syncthreads();

  bf16x8 ka[4], qb[4];
  #pragma unroll
  for (int t = 0; t < 4; t++) {
    ka[t] = *(const bf16x8*)&lk[(t * 16 + l15) * 40 + quad * 8];
    qb[t] = *(const bf16x8*)&lq[(t * 16 + l15) * 40 + quad * 8];
  }
  f32x4 s[4][4];
  const f32x4 fz = {0.0f, 0.0f, 0.0f, 0.0f};
  #pragma unroll
  for (int tm = 0; tm < 4; tm++)
    #pragma unroll
    for (int tr = 0; tr < 4; tr++)
      s[tm][tr] = __builtin_amdgcn_mfma_f32_16x16x32_bf16(ka[tm], qb[tr], fz, 0, 0, 0);

  const float scale = 0.17677669529663687f;
  const float* bt = btab + head * 4096;
  float mx[4] = {-1e30f, -1e30f, -1e30f, -1e30f};
  #pragma unroll
  for (int tm = 0; tm < 4; tm++) {
    int m0 = tm * 16 + quad * 4;
    #pragma unroll
    for (int tr = 0; tr < 4; tr++) {
      int r = tr * 16 + l15;
      #pragma unroll
      for (int j = 0; j < 4; j++) {
        float v = s[tm][tr][j] * scale + bt[(m0 + j) * 64 + r];
        s[tm][tr][j] = v;
        mx[tr] = fmaxf(mx[tr], v);
      }
    }
  }
  #pragma unroll
  for (int tr = 0; tr < 4; tr++) {
    mx[tr] = fmaxf(mx[tr], __shfl_xor(mx[tr], 16));
    mx[tr] = fmaxf(mx[tr], __shfl_xor(mx[tr], 32));
  }
  float sm[4] = {0.f, 0.f, 0.f, 0.f};
  #pragma unroll
  for (int tm = 0; tm < 4; tm++) {
    #pragma unroll
    for (int tr = 0; tr < 4; tr++) {
      int r = tr * 16 + l15;
      float e0 = __expf(s[tm][tr][0] - mx[tr]);
      float e1 = __expf(s[tm][tr][1] - mx[tr]);
      float e2 = __expf(s[tm][tr][2] - mx[tr]);
      float e3 = __expf(s[tm][tr][3] - mx[tr]);
      sm[tr] += (e0 + e1) + (e2 + e3);
      uint2 pk;
      pk.x = (unsigned int)f2bf(e0) | ((unsigned int)f2bf(e1) << 16);
      pk.y = (unsigned int)f2bf(e2) | ((unsigned int)f2bf(e3) << 16);
      *(uint2*)&lp[r * 72 + tm * 16 + quad * 4] = pk;
    }
  }
  #pragma unroll
  for (int tr = 0; tr < 4; tr++) {
    sm[tr] += __shfl_xor(sm[tr], 16);
    sm[tr] += __shfl_xor(sm[tr], 32);
  }
  if (quad == 0) {
    #pragma unroll
    for (int tr = 0; tr < 4; tr++) rsum[tr * 16 + l15] = 1.0f / sm[tr];
  }
  __syncthreads();

  f32x4 o[4][2] = {};
  #pragma unroll
  for (int ks = 0; ks < 2; ks++) {
    bf16x8 vb0 = *(const bf16x8*)&lvt[(l15) * 72 + ks * 32 + quad * 8];
    bf16x8 vb1 = *(const bf16x8*)&lvt[(16 + l15) * 72 + ks * 32 + quad * 8];
    #pragma unroll
    for (int rt = 0; rt < 4; rt++) {
      bf16x8 pf = *(const bf16x8*)&lp[(rt * 16 + l15) * 72 + ks * 32 + quad * 8];
      o[rt][0] = __builtin_amdgcn_mfma_f32_16x16x32_bf16(pf, vb0, o[rt][0], 0, 0, 0);
      o[rt][1] = __builtin_amdgcn_mfma_f32_16x16x32_bf16(pf, vb1, o[rt][1], 0, 0, 0);
    }
  }
  #pragma unroll
  for (int rt = 0; rt < 4; rt++) {
    #pragma unroll
    for (int j = 0; j < 4; j++) {
      int r = rt * 16 + quad * 4 + j;
      if (r < 49) {
        float inv = rsum[r];
        int i = r / 7, jj = r - i * 7;
        int y = wy * 7 + i + 3;   if (y >= 56) y -= 56;
        int xx = wx * 7 + jj + 3; if (xx >= 56) xx -= 56;
        long base = ((long)(b * 3136 + y * 56 + xx)) * 192 + head * 32 + l15;
        attn[base]      = f2bf(o[rt][0][j] * inv);
        attn[base + 16] = f2bf(o[rt][1][j] * inv);
      }
    }
  }
}

extern "C" void kernel_launch(void* const* d_in, const int* in_sizes, int n_in,
                              void* d_out, int out_size, void* d_ws, size_t ws_size,
                              hipStream_t stream) {
  (void)in_sizes; (void)n_in; (void)out_size; (void)ws_size;
  const float* x      = (const float*)d_in[0];
  const float* ln1_g  = (const float*)d_in[3];
  const float* ln1_b  = (const float*)d_in[4];
  const float* qkv_w  = (const float*)d_in[5];
  const float* qkv_b  = (const float*)d_in[6];
  const float* rpb    = (const float*)d_in[7];
  const float* proj_w = (const float*)d_in[8];
  const float* proj_b = (const float*)d_in[9];
  const float* ln2_g  = (const float*)d_in[10];
  const float* ln2_b  = (const float*)d_in[11];
  const float* fc1_w  = (const float*)d_in[12];
  const float* fc1_b  = (const float*)d_in[13];
  const float* fc2_w  = (const float*)d_in[14];
  const float* fc2_b  = (const float*)d_in[15];

  // workspace layout (bytes), M=50176:
  //   [0,            38,535,168)  x2 fp32
  //   [38,535,168,   57,802,752)  hA bf16 (ln1 out; btab overlays after qkv GEMM;
  //                               region rewritten as ln2 out later)
  //   [57,802,752,  115,605,504)  qkv bf16  --+ dead after proj; hid bf16 overlays
  //   [115,605,504, 134,873,088)  attn bf16 --+ [57,802,752, 173,408,256)
  //   [173,408,256, 174,587,904)  bf16 weights
  char* ws = (char*)d_ws;
  float* x2   = (float*)(ws + 0);
  u16* hA     = (u16*)(ws + 38535168);
  float* btab = (float*)(ws + 38535168);   // 98,304 B, live only qkv->attn
  u16* qkv    = (u16*)(ws + 57802752);
  u16* attn   = (u16*)(ws + 115605504);
  u16* hid    = (u16*)(ws + 57802752);
  u16* wbuf   = (u16*)(ws + 173408256);
  u16* qkv_wb  = wbuf;
  u16* proj_wb = wbuf + 110592;
  u16* fc1_wb  = wbuf + 147456;
  u16* fc2_wb  = wbuf + 368640;

  cast_weights<<<dim3(864), 256, 0, stream>>>(qkv_w, proj_w, fc1_w, fc2_w,
                                              qkv_wb, proj_wb, fc1_wb, fc2_wb);
  ln_kernel<<<dim3(12544), 256, 0, stream>>>(x, ln1_g, ln1_b, hA);
  gemm_kernel<0><<<dim3(392, 9), 256, 0, stream>>>(hA, qkv_wb, qkv_b, nullptr,
                                                   qkv, 576, 192);
  build_btab<<<dim3(96), 256, 0, stream>>>(rpb, btab);
  attn_kernel<<<dim3(1536), 256, 0, stream>>>(qkv, btab, attn);
  gemm_kernel<2><<<dim3(392, 3), 256, 0, stream>>>(attn, proj_wb, proj_b, x,
                                                   x2, 192, 192);
  ln_kernel<<<dim3(12544), 256, 0, stream>>>(x2, ln2_g, ln2_b, hA);
  gemm_kernel<1><<<dim3(392, 18), 256, 0, stream>>>(hA, fc1_wb, fc1_b, nullptr,
                                                    hid, 1152, 192);
  gemm_kernel<2><<<dim3(392, 3), 256, 0, stream>>>(hid, fc2_wb, fc2_b, x2,
                                                   (float*)d_out, 192, 1152);
}

// Round 4
// 380.935 us; speedup vs baseline: 1.3307x; 1.1212x over previous
//
#include <hip/hip_runtime.h>

typedef unsigned short u16;
typedef __bf16 bf16x8 __attribute__((ext_vector_type(8)));
typedef float f32x4 __attribute__((ext_vector_type(4)));

#define AS1 __attribute__((address_space(1)))
#define AS3 __attribute__((address_space(3)))

__device__ __forceinline__ void gld16(const void* g, void* l) {
  // 16B per lane: global per-lane gather -> LDS (wave-uniform base + lane*16)
  __builtin_amdgcn_global_load_lds((const AS1 void*)g, (AS3 void*)l, 16, 0, 0);
}

__device__ __forceinline__ u16 f2bf(float f) {
  union { float f; unsigned int u; } v; v.f = f;
  unsigned int u = v.u;
  u += 0x7fffu + ((u >> 16) & 1u);
  return (u16)(u >> 16);
}
__device__ __forceinline__ float bf2f(u16 h) {
  union { unsigned int u; float f; } v; v.u = ((unsigned int)h) << 16; return v.f;
}
// fast GELU: v * sigmoid(v*(1.5957691 + 0.0713548*v^2))  (~1e-3 of exact erf form)
__device__ __forceinline__ float gelu_f(float v) {
  float u = v * (1.5957691216f + 0.0713548163f * v * v);
  return v * __frcp_rn(1.0f + __expf(-u));
}

// ---------------- cast weights fp32 -> bf16 ----------------
__global__ __launch_bounds__(256) void cast_weights(
    const float* __restrict__ w0, const float* __restrict__ w1,
    const float* __restrict__ w2, const float* __restrict__ w3,
    u16* __restrict__ o0, u16* __restrict__ o1,
    u16* __restrict__ o2, u16* __restrict__ o3) {
  int i = blockIdx.x * 256 + threadIdx.x;
  if (i < 110592) o0[i] = f2bf(w0[i]);   // qkv_w 576x192
  if (i < 36864)  o1[i] = f2bf(w1[i]);   // proj_w 192x192
  if (i < 221184) o2[i] = f2bf(w2[i]);   // fc1_w 1152x192
  if (i < 221184) o3[i] = f2bf(w3[i]);   // fc2_w 192x1152
}

// ---------------- bias table [6][64(key m)][64(query r)]; key>=49 -> -1e30 ----
__global__ __launch_bounds__(256) void build_btab(
    const float* __restrict__ rpb, float* __restrict__ btab) {
  int id = blockIdx.x * 256 + threadIdx.x;   // 96*256 = 24576
  int head = id >> 12;
  int m = (id >> 6) & 63;
  int r = id & 63;
  float v;
  if (m >= 49) v = -1e30f;                   // key mask folds into bias
  else if (r >= 49) v = 0.0f;
  else {
    int mi = m / 7, mj = m - mi * 7;
    int ri = r / 7, rj = r - ri * 7;
    v = rpb[((ri - mi + 6) * 13 + (rj - mj + 6)) * 6 + head];
  }
  btab[id] = v;
}

// ---------------- layernorm (fp32 in, bf16 out), 1 wave per row of 192 ----------------
__global__ __launch_bounds__(256) void ln_kernel(
    const float* __restrict__ x, const float* __restrict__ g,
    const float* __restrict__ b, u16* __restrict__ out) {
  int row = blockIdx.x * 4 + (threadIdx.x >> 6);
  int lane = threadIdx.x & 63;
  const float* xr = x + (long)row * 192;
  float e0 = xr[lane], e1 = xr[lane + 64], e2 = xr[lane + 128];
  float s = e0 + e1 + e2;
  #pragma unroll
  for (int o = 1; o < 64; o <<= 1) s += __shfl_xor(s, o);
  float mean = s * (1.0f / 192.0f);
  float d0 = e0 - mean, d1 = e1 - mean, d2 = e2 - mean;
  float q = d0 * d0 + d1 * d1 + d2 * d2;
  #pragma unroll
  for (int o = 1; o < 64; o <<= 1) q += __shfl_xor(q, o);
  float rstd = rsqrtf(q * (1.0f / 192.0f) + 1e-5f);
  u16* orow = out + (long)row * 192;
  orow[lane]       = f2bf(d0 * rstd * g[lane]       + b[lane]);
  orow[lane + 64]  = f2bf(d1 * rstd * g[lane + 64]  + b[lane + 64]);
  orow[lane + 128] = f2bf(d2 * rstd * g[lane + 128] + b[lane + 128]);
}

// ---------------- MFMA GEMM: out[M,N] = A[M,K] @ W[N,K]^T + bias ----------------
// Block tile 128x64, 4 waves 2x2 (wave tile 64x32), 16x16x32 bf16 MFMA.
// K chunked by 96, staged fragment-ordered via global_load_lds width-16
// (conflict-free ds_read_b128 at lane*16). LDS = 36,864 B -> 4 blocks/CU so
// co-resident blocks cover each other's barrier drains. K % 96 == 0 required.
// Epilogue: acc -> LDS fp32 [128][66] -> full-line coalesced stores.
// MODE 0: store bf16. MODE 1: fast-GELU -> bf16. MODE 2: +resid(fp32) -> fp32.
template<int MODE>
__global__ __launch_bounds__(256, 4) void gemm_kernel(
    const u16* __restrict__ A, const u16* __restrict__ W,
    const float* __restrict__ bias, const float* __restrict__ resid,
    void* __restrict__ out, int N, int K) {
  // per chunk: A = 24 tiles (grp 0..7 x kt 0..2) of 512 u16; B = 12 tiles
  __shared__ u16 lds[18432];           // 36,864 B
  float* ct = (float*)lds;             // epilogue overlay: 128 x 66 fp32 (33,792 B)
  int tid = threadIdx.x;
  int wave = tid >> 6, lane = tid & 63;
  int wm = wave >> 1, wn = wave & 1;
  int quad = lane >> 4, l15 = lane & 15;
  long bm = (long)blockIdx.x * 128;
  int bn = blockIdx.y * 64;

  f32x4 acc[4][2] = {};
  for (int kc = 0; kc < K; kc += 96) {
    if (kc > 0) __syncthreads();       // LDS reuse across chunks
    // ---- stage: 36 tiles, 9 per wave, fragment-ordered ----
    int t0 = wave * 9;
    #pragma unroll
    for (int ti = 0; ti < 9; ti++) {
      int t = t0 + ti;
      int isB = t >= 24;
      int tt = isB ? t - 24 : t;
      int grp = tt / 3, kt = tt - grp * 3;
      const u16* g = isB
          ? (W + (long)(bn + grp * 16 + l15) * K + kc + kt * 32 + quad * 8)
          : (A + (bm + grp * 16 + l15) * K + kc + kt * 32 + quad * 8);
      gld16(g, &lds[(isB ? 12288 : 0) + tt * 512]);
    }
    __syncthreads();
    // ---- compute: 3 kt steps x 8 MFMA ----
    #pragma unroll
    for (int kt = 0; kt < 3; kt++) {
      bf16x8 af[4], bfr[2];
      #pragma unroll
      for (int mt = 0; mt < 4; mt++)
        af[mt] = *(const bf16x8*)&lds[((wm * 4 + mt) * 3 + kt) * 512 + lane * 8];
      #pragma unroll
      for (int nt = 0; nt < 2; nt++)
        bfr[nt] = *(const bf16x8*)&lds[12288 + ((wn * 2 + nt) * 3 + kt) * 512 + lane * 8];
      #pragma unroll
      for (int mt = 0; mt < 4; mt++)
        #pragma unroll
        for (int nt = 0; nt < 2; nt++)
          acc[mt][nt] = __builtin_amdgcn_mfma_f32_16x16x32_bf16(af[mt], bfr[nt], acc[mt][nt], 0, 0, 0);
    }
  }
  __syncthreads();
  // ---- epilogue: acc(+bias) -> LDS fp32 [128][66] ----
  #pragma unroll
  for (int nt = 0; nt < 2; nt++) {
    int col = wn * 32 + nt * 16 + l15;
    float bi = bias[bn + col];
    #pragma unroll
    for (int mt = 0; mt < 4; mt++) {
      int row0 = wm * 64 + mt * 16 + quad * 4;
      #pragma unroll
      for (int j = 0; j < 4; j++)
        ct[(row0 + j) * 66 + col] = acc[mt][nt][j] + bi;
    }
  }
  __syncthreads();
  // ---- coalesced writeout: 2048 float4 chunks (128 rows x 16 groups) ----
  #pragma unroll
  for (int it = 0; it < 8; it++) {
    int c = it * 256 + tid;
    int row = c >> 4, cg = (c & 15) * 4;
    float4 v = *(const float4*)&ct[row * 66 + cg];
    long idx = (bm + row) * (long)N + bn + cg;
    if (MODE == 2) {
      const float4 rv = *(const float4*)(resid + idx);
      v.x += rv.x; v.y += rv.y; v.z += rv.z; v.w += rv.w;
      *(float4*)((float*)out + idx) = v;
    } else {
      if (MODE == 1) {
        v.x = gelu_f(v.x); v.y = gelu_f(v.y); v.z = gelu_f(v.z); v.w = gelu_f(v.w);
      }
      uint2 pk;
      pk.x = (unsigned int)f2bf(v.x) | ((unsigned int)f2bf(v.y) << 16);
      pk.y = (unsigned int)f2bf(v.z) | ((unsigned int)f2bf(v.w) << 16);
      *(uint2*)((u16*)out + idx) = pk;
    }
  }
}

// ---------------- MFMA windowed attention: 1 wave per (window, head) ----------------
__global__ __launch_bounds__(256) void attn_kernel(
    const u16* __restrict__ qkv, const float* __restrict__ btab,
    u16* __restrict__ attn) {
  __shared__ u16 lds[4 * 7552];   // 60416 B
  int tid = threadIdx.x;
  int wave = tid >> 6, lane = tid & 63;
  int quad = lane >> 4, l15 = lane & 15;
  int w = blockIdx.x * 4 + wave;
  int win = w / 6, head = w - win * 6;
  int b = win >> 6, wy = (win >> 3) & 7, wx = win & 7;
  u16* lq = lds + wave * 7552;
  u16* lk = lq + 2560;
  u16* lvt = lq + 5120;
  float* rsum = (float*)(lq + 7424);
  u16* lp = lq;

  #pragma unroll
  for (int p = 0; p < 4; p++) {
    int n = p * 16 + (lane >> 2);
    int qtr = (lane & 3) * 8;
    uint4 qv = {}, kv = {}, vv = {};
    if (n < 49) {
      int i = n / 7, j = n - i * 7;
      int y = wy * 7 + i + 3;  if (y >= 56) y -= 56;
      int xx = wx * 7 + j + 3; if (xx >= 56) xx -= 56;
      long base = ((long)(b * 3136 + y * 56 + xx)) * 576 + head * 32 + qtr;
      qv = *(const uint4*)(qkv + base);
      kv = *(const uint4*)(qkv + base + 192);
      vv = *(const uint4*)(qkv + base + 384);
    }
    *(uint4*)&lq[n * 40 + qtr] = qv;
    *(uint4*)&lk[n * 40 + qtr] = kv;
    const u16* vp = (const u16*)&vv;
    #pragma unroll
    for (int d = 0; d < 8; d++) lvt[(qtr + d) * 72 + n] = vp[d];
  }
  __syncthreads();

  bf16x8 ka[4], qb[4];
  #pragma unroll
  for (int t = 0; t < 4; t++) {
    ka[t] = *(const bf16x8*)&lk[(t * 16 + l15) * 40 + quad * 8];
    qb[t] = *(const bf16x8*)&lq[(t * 16 + l15) * 40 + quad * 8];
  }
  f32x4 s[4][4];
  const f32x4 fz = {0.0f, 0.0f, 0.0f, 0.0f};
  #pragma unroll
  for (int tm = 0; tm < 4; tm++)
    #pragma unroll
    for (int tr = 0; tr < 4; tr++)
      s[tm][tr] = __builtin_amdgcn_mfma_f32_16x16x32_bf16(ka[tm], qb[tr], fz, 0, 0, 0);

  const float scale = 0.17677669529663687f;
  const float* bt = btab + head * 4096;
  float mx[4] = {-1e30f, -1e30f, -1e30f, -1e30f};
  #pragma unroll
  for (int tm = 0; tm < 4; tm++) {
    int m0 = tm * 16 + quad * 4;
    #pragma unroll
    for (int tr = 0; tr < 4; tr++) {
      int r = tr * 16 + l15;
      #pragma unroll
      for (int j = 0; j < 4; j++) {
        float v = s[tm][tr][j] * scale + bt[(m0 + j) * 64 + r];
        s[tm][tr][j] = v;
        mx[tr] = fmaxf(mx[tr], v);
      }
    }
  }
  #pragma unroll
  for (int tr = 0; tr < 4; tr++) {
    mx[tr] = fmaxf(mx[tr], __shfl_xor(mx[tr], 16));
    mx[tr] = fmaxf(mx[tr], __shfl_xor(mx[tr], 32));
  }
  float sm[4] = {0.f, 0.f, 0.f, 0.f};
  #pragma unroll
  for (int tm = 0; tm < 4; tm++) {
    #pragma unroll
    for (int tr = 0; tr < 4; tr++) {
      int r = tr * 16 + l15;
      float e0 = __expf(s[tm][tr][0] - mx[tr]);
      float e1 = __expf(s[tm][tr][1] - mx[tr]);
      float e2 = __expf(s[tm][tr][2] - mx[tr]);
      float e3 = __expf(s[tm][tr][3] - mx[tr]);
      sm[tr] += (e0 + e1) + (e2 + e3);
      uint2 pk;
      pk.x = (unsigned int)f2bf(e0) | ((unsigned int)f2bf(e1) << 16);
      pk.y = (unsigned int)f2bf(e2) | ((unsigned int)f2bf(e3) << 16);
      *(uint2*)&lp[r * 72 + tm * 16 + quad * 4] = pk;
    }
  }
  #pragma unroll
  for (int tr = 0; tr < 4; tr++) {
    sm[tr] += __shfl_xor(sm[tr], 16);
    sm[tr] += __shfl_xor(sm[tr], 32);
  }
  if (quad == 0) {
    #pragma unroll
    for (int tr = 0; tr < 4; tr++) rsum[tr * 16 + l15] = 1.0f / sm[tr];
  }
  __syncthreads();

  f32x4 o[4][2] = {};
  #pragma unroll
  for (int ks = 0; ks < 2; ks++) {
    bf16x8 vb0 = *(const bf16x8*)&lvt[(l15) * 72 + ks * 32 + quad * 8];
    bf16x8 vb1 = *(const bf16x8*)&lvt[(16 + l15) * 72 + ks * 32 + quad * 8];
    #pragma unroll
    for (int rt = 0; rt < 4; rt++) {
      bf16x8 pf = *(const bf16x8*)&lp[(rt * 16 + l15) * 72 + ks * 32 + quad * 8];
      o[rt][0] = __builtin_amdgcn_mfma_f32_16x16x32_bf16(pf, vb0, o[rt][0], 0, 0, 0);
      o[rt][1] = __builtin_amdgcn_mfma_f32_16x16x32_bf16(pf, vb1, o[rt][1], 0, 0, 0);
    }
  }
  #pragma unroll
  for (int rt = 0; rt < 4; rt++) {
    #pragma unroll
    for (int j = 0; j < 4; j++) {
      int r = rt * 16 + quad * 4 + j;
      if (r < 49) {
        float inv = rsum[r];
        int i = r / 7, jj = r - i * 7;
        int y = wy * 7 + i + 3;   if (y >= 56) y -= 56;
        int xx = wx * 7 + jj + 3; if (xx >= 56) xx -= 56;
        long base = ((long)(b * 3136 + y * 56 + xx)) * 192 + head * 32 + l15;
        attn[base]      = f2bf(o[rt][0][j] * inv);
        attn[base + 16] = f2bf(o[rt][1][j] * inv);
      }
    }
  }
}

extern "C" void kernel_launch(void* const* d_in, const int* in_sizes, int n_in,
                              void* d_out, int out_size, void* d_ws, size_t ws_size,
                              hipStream_t stream) {
  (void)in_sizes; (void)n_in; (void)out_size; (void)ws_size;
  const float* x      = (const float*)d_in[0];
  const float* ln1_g  = (const float*)d_in[3];
  const float* ln1_b  = (const float*)d_in[4];
  const float* qkv_w  = (const float*)d_in[5];
  const float* qkv_b  = (const float*)d_in[6];
  const float* rpb    = (const float*)d_in[7];
  const float* proj_w = (const float*)d_in[8];
  const float* proj_b = (const float*)d_in[9];
  const float* ln2_g  = (const float*)d_in[10];
  const float* ln2_b  = (const float*)d_in[11];
  const float* fc1_w  = (const float*)d_in[12];
  const float* fc1_b  = (const float*)d_in[13];
  const float* fc2_w  = (const float*)d_in[14];
  const float* fc2_b  = (const float*)d_in[15];

  // workspace layout (bytes), M=50176:
  //   [0,            38,535,168)  x2 fp32
  //   [38,535,168,   57,802,752)  hA bf16 (ln1 out; btab overlays after qkv GEMM;
  //                               region rewritten as ln2 out later)
  //   [57,802,752,  115,605,504)  qkv bf16  --+ dead after proj; hid bf16 overlays
  //   [115,605,504, 134,873,088)  attn bf16 --+ [57,802,752, 173,408,256)
  //   [173,408,256, 174,587,904)  bf16 weights
  char* ws = (char*)d_ws;
  float* x2   = (float*)(ws + 0);
  u16* hA     = (u16*)(ws + 38535168);
  float* btab = (float*)(ws + 38535168);   // 98,304 B, live only qkv->attn
  u16* qkv    = (u16*)(ws + 57802752);
  u16* attn   = (u16*)(ws + 115605504);
  u16* hid    = (u16*)(ws + 57802752);
  u16* wbuf   = (u16*)(ws + 173408256);
  u16* qkv_wb  = wbuf;
  u16* proj_wb = wbuf + 110592;
  u16* fc1_wb  = wbuf + 147456;
  u16* fc2_wb  = wbuf + 368640;

  cast_weights<<<dim3(864), 256, 0, stream>>>(qkv_w, proj_w, fc1_w, fc2_w,
                                              qkv_wb, proj_wb, fc1_wb, fc2_wb);
  ln_kernel<<<dim3(12544), 256, 0, stream>>>(x, ln1_g, ln1_b, hA);
  gemm_kernel<0><<<dim3(392, 9), 256, 0, stream>>>(hA, qkv_wb, qkv_b, nullptr,
                                                   qkv, 576, 192);
  build_btab<<<dim3(96), 256, 0, stream>>>(rpb, btab);
  attn_kernel<<<dim3(1536), 256, 0, stream>>>(qkv, btab, attn);
  gemm_kernel<2><<<dim3(392, 3), 256, 0, stream>>>(attn, proj_wb, proj_b, x,
                                                   x2, 192, 192);
  ln_kernel<<<dim3(12544), 256, 0, stream>>>(x2, ln2_g, ln2_b, hA);
  gemm_kernel<1><<<dim3(392, 18), 256, 0, stream>>>(hA, fc1_wb, fc1_b, nullptr,
                                                    hid, 1152, 192);
  gemm_kernel<2><<<dim3(392, 3), 256, 0, stream>>>(hid, fc2_wb, fc2_b, x2,
                                                   (float*)d_out, 192, 1152);
}

// Round 5
// 352.946 us; speedup vs baseline: 1.4362x; 1.0793x over previous
//
#include <hip/hip_runtime.h>

typedef unsigned short u16;
typedef __bf16 bf16x8 __attribute__((ext_vector_type(8)));
typedef __bf16 bf16x2_t __attribute__((ext_vector_type(2)));
typedef float f32x4 __attribute__((ext_vector_type(4)));

#define AS1 __attribute__((address_space(1)))
#define AS3 __attribute__((address_space(3)))

__device__ __forceinline__ void gld16(const void* g, void* l) {
  // 16B per lane: global per-lane gather -> LDS (wave-uniform base + lane*16)
  __builtin_amdgcn_global_load_lds((const AS1 void*)g, (AS3 void*)l, 16, 0, 0);
}

__device__ __forceinline__ u16 f2bf(float f) {
  union { float f; unsigned int u; } v; v.f = f;
  unsigned int u = v.u;
  u += 0x7fffu + ((u >> 16) & 1u);
  return (u16)(u >> 16);
}
__device__ __forceinline__ float bf2f(u16 h) {
  union { unsigned int u; float f; } v; v.u = ((unsigned int)h) << 16; return v.f;
}
// pack 2 fp32 -> 2 bf16 in one HW instr where available
__device__ __forceinline__ unsigned int pk2(float a, float b) {
#if __has_builtin(__builtin_amdgcn_cvt_pk_bf16_f32)
  union { bf16x2_t v; unsigned int u; } c;
  c.v = __builtin_amdgcn_cvt_pk_bf16_f32(a, b);
  return c.u;
#else
  return (unsigned int)f2bf(a) | ((unsigned int)f2bf(b) << 16);
#endif
}
// fast GELU: v * sigmoid(v*(1.5957691 + 0.0713548*v^2)); raw v_rcp (1 instr)
__device__ __forceinline__ float gelu_f(float v) {
  float u = v * (1.5957691216f + 0.0713548163f * v * v);
  return v * __builtin_amdgcn_rcpf(1.0f + __expf(-u));
}

// ---------------- cast weights fp32 -> bf16 ----------------
// proj_w gets head-interleaved column permutation to match attn's packed stores:
// attn lane holds (d, d+16) pairs -> stored at cols (2d, 2d+1) within the head.
__global__ __launch_bounds__(256) void cast_weights(
    const float* __restrict__ w0, const float* __restrict__ w1,
    const float* __restrict__ w2, const float* __restrict__ w3,
    u16* __restrict__ o0, u16* __restrict__ o1,
    u16* __restrict__ o2, u16* __restrict__ o3) {
  int i = blockIdx.x * 256 + threadIdx.x;
  if (i < 110592) o0[i] = f2bf(w0[i]);   // qkv_w 576x192
  if (i < 36864) {                        // proj_w 192x192, k-permuted
    int n = i / 192, kp = i - n * 192;
    int h = kp >> 5, dp = kp & 31;
    int d = (dp & 1) ? ((dp >> 1) + 16) : (dp >> 1);
    o1[i] = f2bf(w1[n * 192 + h * 32 + d]);
  }
  if (i < 221184) o2[i] = f2bf(w2[i]);   // fc1_w 1152x192
  if (i < 221184) o3[i] = f2bf(w3[i]);   // fc2_w 192x1152
}

// ---------------- bias table [6][64(key m)][64(query r)]; key>=49 -> -1e30 ----
__global__ __launch_bounds__(256) void build_btab(
    const float* __restrict__ rpb, float* __restrict__ btab) {
  int id = blockIdx.x * 256 + threadIdx.x;   // 96*256 = 24576
  int head = id >> 12;
  int m = (id >> 6) & 63;
  int r = id & 63;
  float v;
  if (m >= 49) v = -1e30f;                   // key mask folds into bias
  else if (r >= 49) v = 0.0f;
  else {
    int mi = m / 7, mj = m - mi * 7;
    int ri = r / 7, rj = r - ri * 7;
    v = rpb[((ri - mi + 6) * 13 + (rj - mj + 6)) * 6 + head];
  }
  btab[id] = v;
}

// ---------------- layernorm (fp32 in, bf16 out), 1 wave per row of 192 ----------------
__global__ __launch_bounds__(256) void ln_kernel(
    const float* __restrict__ x, const float* __restrict__ g,
    const float* __restrict__ b, u16* __restrict__ out) {
  int row = blockIdx.x * 4 + (threadIdx.x >> 6);
  int lane = threadIdx.x & 63;
  const float* xr = x + (long)row * 192;
  float e0 = xr[lane], e1 = xr[lane + 64], e2 = xr[lane + 128];
  float s = e0 + e1 + e2;
  #pragma unroll
  for (int o = 1; o < 64; o <<= 1) s += __shfl_xor(s, o);
  float mean = s * (1.0f / 192.0f);
  float d0 = e0 - mean, d1 = e1 - mean, d2 = e2 - mean;
  float q = d0 * d0 + d1 * d1 + d2 * d2;
  #pragma unroll
  for (int o = 1; o < 64; o <<= 1) q += __shfl_xor(q, o);
  float rstd = rsqrtf(q * (1.0f / 192.0f) + 1e-5f);
  u16* orow = out + (long)row * 192;
  orow[lane]       = f2bf(d0 * rstd * g[lane]       + b[lane]);
  orow[lane + 64]  = f2bf(d1 * rstd * g[lane + 64]  + b[lane + 64]);
  orow[lane + 128] = f2bf(d2 * rstd * g[lane + 128] + b[lane + 128]);
}

// ---------------- MFMA GEMM: out[M,N] = A[M,K] @ W[N,K]^T + bias ----------------
// Block tile 128x96, 4 waves 2x2 (wave tile 64x48), 16x16x32 bf16 MFMA.
// K chunked by 96, staged fragment-ordered via global_load_lds width-16
// (conflict-free ds_read_b128 at lane*16). LDS 51,200 B -> 3 blocks/CU.
// Epilogue: acc -> LDS fp32 [128][100] -> full-line coalesced stores.
// MODE 0: store bf16. MODE 1: fast-GELU -> bf16. MODE 2: +resid(fp32) -> fp32.
// Requires K % 96 == 0, N % 96 == 0, M % 128 == 0.
template<int MODE>
__global__ __launch_bounds__(256, 3) void gemm_kernel(
    const u16* __restrict__ A, const u16* __restrict__ W,
    const float* __restrict__ bias, const float* __restrict__ resid,
    void* __restrict__ out, int N, int K) {
  // staging: A = 24 tiles (grp 0..7 x kt 0..2) of 512 u16 at 0;
  //          B = 18 tiles (grp 0..5 x kt 0..2) at u16 offset 12288. (43,008 B)
  __shared__ u16 lds[25600];           // 51,200 B (epilogue 128x100 f32 overlay)
  float* ct = (float*)lds;
  const int tid = threadIdx.x;
  const int wave = tid >> 6, lane = tid & 63;
  const int wm = wave >> 1, wn = wave & 1;
  const int quad = lane >> 4, l15 = lane & 15;
  const long bm = (long)blockIdx.x * 128;
  const int bn = blockIdx.y * 96;

  f32x4 acc[4][3] = {};
  for (int kc = 0; kc < K; kc += 96) {
    if (kc) __syncthreads();           // LDS reuse across chunks
    for (int t = wave; t < 42; t += 4) {
      int isB = t >= 24;
      int tt = isB ? t - 24 : t;
      int grp = tt / 3, kt = tt - grp * 3;
      const u16* g = isB
          ? (W + (long)(bn + grp * 16 + l15) * K + kc + kt * 32 + quad * 8)
          : (A + (bm + grp * 16 + l15) * K + kc + kt * 32 + quad * 8);
      gld16(g, &lds[(isB ? 12288 : 0) + tt * 512]);
    }
    __syncthreads();
    #pragma unroll
    for (int kt = 0; kt < 3; kt++) {
      bf16x8 af[4], bfr[3];
      #pragma unroll
      for (int mt = 0; mt < 4; mt++)
        af[mt] = *(const bf16x8*)&lds[((wm * 4 + mt) * 3 + kt) * 512 + lane * 8];
      #pragma unroll
      for (int nt = 0; nt < 3; nt++)
        bfr[nt] = *(const bf16x8*)&lds[12288 + ((wn * 3 + nt) * 3 + kt) * 512 + lane * 8];
      #pragma unroll
      for (int mt = 0; mt < 4; mt++)
        #pragma unroll
        for (int nt = 0; nt < 3; nt++)
          acc[mt][nt] = __builtin_amdgcn_mfma_f32_16x16x32_bf16(af[mt], bfr[nt], acc[mt][nt], 0, 0, 0);
    }
  }
  __syncthreads();
  // ---- epilogue: acc(+bias) -> LDS fp32 [128][100] (2-way max on banks) ----
  #pragma unroll
  for (int nt = 0; nt < 3; nt++) {
    int col = wn * 48 + nt * 16 + l15;
    float bi = bias[bn + col];
    #pragma unroll
    for (int mt = 0; mt < 4; mt++) {
      int row0 = wm * 64 + mt * 16 + quad * 4;
      #pragma unroll
      for (int j = 0; j < 4; j++)
        ct[(row0 + j) * 100 + col] = acc[mt][nt][j] + bi;
    }
  }
  __syncthreads();
  // ---- coalesced writeout: 3072 float4 chunks (128 rows x 24 groups) ----
  #pragma unroll
  for (int it = 0; it < 12; it++) {
    int c = it * 256 + tid;
    int row = c / 24, i = c - row * 24;
    float4 v = *(const float4*)&ct[row * 100 + i * 4];
    long idx = (bm + row) * (long)N + bn + i * 4;
    if (MODE == 2) {
      const float4 rv = *(const float4*)(resid + idx);
      v.x += rv.x; v.y += rv.y; v.z += rv.z; v.w += rv.w;
      *(float4*)((float*)out + idx) = v;
    } else {
      if (MODE == 1) {
        v.x = gelu_f(v.x); v.y = gelu_f(v.y); v.z = gelu_f(v.z); v.w = gelu_f(v.w);
      }
      uint2 pk;
      pk.x = pk2(v.x, v.y);
      pk.y = pk2(v.z, v.w);
      *(uint2*)((u16*)out + idx) = pk;
    }
  }
}

// ---------------- MFMA windowed attention: 1 wave per (window, head) ----------------
// Barrier-free: all LDS regions are wave-private. Q/K fragments load DIRECTLY
// from global (frag 16B/lane is contiguous); only V (transpose) and P round-trip
// LDS. Output packed 4B stores in head-interleaved column order (proj_w cast
// permuted to match).
__global__ __launch_bounds__(256) void attn_kernel(
    const u16* __restrict__ qkv, const float* __restrict__ btab,
    u16* __restrict__ attn) {
  // per-wave u16: P 64x72 = 4608 | Vt 32x72 = 2304 | rsum 64 f32 = 128
  __shared__ u16 lds[4 * 7040];   // 56,320 B -> 2 blocks/CU
  int tid = threadIdx.x;
  int wave = tid >> 6, lane = tid & 63;
  int quad = lane >> 4, l15 = lane & 15;
  int w = blockIdx.x * 4 + wave;
  int win = w / 6, head = w - win * 6;
  int b = win >> 6, wy = (win >> 3) & 7, wx = win & 7;
  u16* lp = lds + wave * 7040;
  u16* lvt = lp + 4608;
  float* rsum = (float*)(lp + 6912);

  // ---- direct Q/K fragment loads + V transpose-stage (rows >=49 zero) ----
  bf16x8 qb[4], ka[4];
  #pragma unroll
  for (int t = 0; t < 4; t++) {
    int n = t * 16 + l15;
    uint4 qv = {0, 0, 0, 0}, kv = {0, 0, 0, 0}, vv = {0, 0, 0, 0};
    if (n < 49) {
      int i = n / 7, j = n - i * 7;
      int y = wy * 7 + i + 3;  if (y >= 56) y -= 56;
      int xx = wx * 7 + j + 3; if (xx >= 56) xx -= 56;
      long base = ((long)(b * 3136 + y * 56 + xx)) * 576 + head * 32 + quad * 8;
      qv = *(const uint4*)(qkv + base);
      kv = *(const uint4*)(qkv + base + 192);
      vv = *(const uint4*)(qkv + base + 384);
    }
    qb[t] = *(const bf16x8*)&qv;
    ka[t] = *(const bf16x8*)&kv;
    const u16* vp = (const u16*)&vv;
    #pragma unroll
    for (int d = 0; d < 8; d++) lvt[(quad * 8 + d) * 72 + n] = vp[d];
  }

  // ---- S^T[key m][query r] = K @ Q^T ----
  f32x4 s[4][4];
  const f32x4 fz = {0.0f, 0.0f, 0.0f, 0.0f};
  #pragma unroll
  for (int tm = 0; tm < 4; tm++)
    #pragma unroll
    for (int tr = 0; tr < 4; tr++)
      s[tm][tr] = __builtin_amdgcn_mfma_f32_16x16x32_bf16(ka[tm], qb[tr], fz, 0, 0, 0);

  const float scale = 0.17677669529663687f;  // 32^-0.5
  const float* bt = btab + head * 4096;
  float mx[4] = {-1e30f, -1e30f, -1e30f, -1e30f};
  #pragma unroll
  for (int tm = 0; tm < 4; tm++) {
    int m0 = tm * 16 + quad * 4;
    #pragma unroll
    for (int tr = 0; tr < 4; tr++) {
      int r = tr * 16 + l15;
      #pragma unroll
      for (int j = 0; j < 4; j++) {
        float v = s[tm][tr][j] * scale + bt[(m0 + j) * 64 + r];
        s[tm][tr][j] = v;
        mx[tr] = fmaxf(mx[tr], v);
      }
    }
  }
  #pragma unroll
  for (int tr = 0; tr < 4; tr++) {
    mx[tr] = fmaxf(mx[tr], __shfl_xor(mx[tr], 16));
    mx[tr] = fmaxf(mx[tr], __shfl_xor(mx[tr], 32));
  }
  float sm[4] = {0.f, 0.f, 0.f, 0.f};
  #pragma unroll
  for (int tm = 0; tm < 4; tm++) {
    #pragma unroll
    for (int tr = 0; tr < 4; tr++) {
      int r = tr * 16 + l15;
      float e0 = __expf(s[tm][tr][0] - mx[tr]);
      float e1 = __expf(s[tm][tr][1] - mx[tr]);
      float e2 = __expf(s[tm][tr][2] - mx[tr]);
      float e3 = __expf(s[tm][tr][3] - mx[tr]);
      sm[tr] += (e0 + e1) + (e2 + e3);
      uint2 pk;
      pk.x = pk2(e0, e1);
      pk.y = pk2(e2, e3);
      *(uint2*)&lp[r * 72 + tm * 16 + quad * 4] = pk;
    }
  }
  #pragma unroll
  for (int tr = 0; tr < 4; tr++) {
    sm[tr] += __shfl_xor(sm[tr], 16);
    sm[tr] += __shfl_xor(sm[tr], 32);
  }
  if (quad == 0) {
    #pragma unroll
    for (int tr = 0; tr < 4; tr++) rsum[tr * 16 + l15] = __builtin_amdgcn_rcpf(sm[tr]);
  }

  // ---- O[r][d] = P @ V via Vt (all same-wave LDS; lgkmcnt orders it) ----
  f32x4 o[4][2] = {};
  #pragma unroll
  for (int ks = 0; ks < 2; ks++) {
    bf16x8 vb0 = *(const bf16x8*)&lvt[(l15) * 72 + ks * 32 + quad * 8];
    bf16x8 vb1 = *(const bf16x8*)&lvt[(16 + l15) * 72 + ks * 32 + quad * 8];
    #pragma unroll
    for (int rt = 0; rt < 4; rt++) {
      bf16x8 pf = *(const bf16x8*)&lp[(rt * 16 + l15) * 72 + ks * 32 + quad * 8];
      o[rt][0] = __builtin_amdgcn_mfma_f32_16x16x32_bf16(pf, vb0, o[rt][0], 0, 0, 0);
      o[rt][1] = __builtin_amdgcn_mfma_f32_16x16x32_bf16(pf, vb1, o[rt][1], 0, 0, 0);
    }
  }
  // ---- normalize + packed scatter (cols head*32 + 2*l15, +1) ----
  #pragma unroll
  for (int rt = 0; rt < 4; rt++) {
    #pragma unroll
    for (int j = 0; j < 4; j++) {
      int r = rt * 16 + quad * 4 + j;
      if (r < 49) {
        float inv = rsum[r];
        int i = r / 7, jj = r - i * 7;
        int y = wy * 7 + i + 3;   if (y >= 56) y -= 56;
        int xx = wx * 7 + jj + 3; if (xx >= 56) xx -= 56;
        long base = ((long)(b * 3136 + y * 56 + xx)) * 192 + head * 32 + 2 * l15;
        *(unsigned int*)&attn[base] = pk2(o[rt][0][j] * inv, o[rt][1][j] * inv);
      }
    }
  }
}

extern "C" void kernel_launch(void* const* d_in, const int* in_sizes, int n_in,
                              void* d_out, int out_size, void* d_ws, size_t ws_size,
                              hipStream_t stream) {
  (void)in_sizes; (void)n_in; (void)out_size; (void)ws_size;
  const float* x      = (const float*)d_in[0];
  const float* ln1_g  = (const float*)d_in[3];
  const float* ln1_b  = (const float*)d_in[4];
  const float* qkv_w  = (const float*)d_in[5];
  const float* qkv_b  = (const float*)d_in[6];
  const float* rpb    = (const float*)d_in[7];
  const float* proj_w = (const float*)d_in[8];
  const float* proj_b = (const float*)d_in[9];
  const float* ln2_g  = (const float*)d_in[10];
  const float* ln2_b  = (const float*)d_in[11];
  const float* fc1_w  = (const float*)d_in[12];
  const float* fc1_b  = (const float*)d_in[13];
  const float* fc2_w  = (const float*)d_in[14];
  const float* fc2_b  = (const float*)d_in[15];

  // workspace layout (bytes), M=50176:
  //   [0,            38,535,168)  x2 fp32
  //   [38,535,168,   57,802,752)  hA bf16 (ln1 out; btab overlays after qkv GEMM;
  //                               region rewritten as ln2 out later)
  //   [57,802,752,  115,605,504)  qkv bf16  --+ dead after proj; hid bf16 overlays
  //   [115,605,504, 134,873,088)  attn bf16 --+ [57,802,752, 173,408,256)
  //   [173,408,256, 174,587,904)  bf16 weights
  char* ws = (char*)d_ws;
  float* x2   = (float*)(ws + 0);
  u16* hA     = (u16*)(ws + 38535168);
  float* btab = (float*)(ws + 38535168);   // 98,304 B, live only qkv->attn
  u16* qkv    = (u16*)(ws + 57802752);
  u16* attn   = (u16*)(ws + 115605504);
  u16* hid    = (u16*)(ws + 57802752);
  u16* wbuf   = (u16*)(ws + 173408256);
  u16* qkv_wb  = wbuf;
  u16* proj_wb = wbuf + 110592;
  u16* fc1_wb  = wbuf + 147456;
  u16* fc2_wb  = wbuf + 368640;

  cast_weights<<<dim3(864), 256, 0, stream>>>(qkv_w, proj_w, fc1_w, fc2_w,
                                              qkv_wb, proj_wb, fc1_wb, fc2_wb);
  ln_kernel<<<dim3(12544), 256, 0, stream>>>(x, ln1_g, ln1_b, hA);
  gemm_kernel<0><<<dim3(392, 6), 256, 0, stream>>>(hA, qkv_wb, qkv_b, nullptr,
                                                   qkv, 576, 192);
  build_btab<<<dim3(96), 256, 0, stream>>>(rpb, btab);
  attn_kernel<<<dim3(1536), 256, 0, stream>>>(qkv, btab, attn);
  gemm_kernel<2><<<dim3(392, 2), 256, 0, stream>>>(attn, proj_wb, proj_b, x,
                                                   x2, 192, 192);
  ln_kernel<<<dim3(12544), 256, 0, stream>>>(x2, ln2_g, ln2_b, hA);
  gemm_kernel<1><<<dim3(392, 12), 256, 0, stream>>>(hA, fc1_wb, fc1_b, nullptr,
                                                    hid, 1152, 192);
  gemm_kernel<2><<<dim3(392, 2), 256, 0, stream>>>(hid, fc2_wb, fc2_b, x2,
                                                   (float*)d_out, 192, 1152);
}